// Round 6
// baseline (371.963 us; speedup 1.0000x reference)
//
#include <hip/hip_runtime.h>

// NetVLAD — round 8: kill the pressure spill (load-at-use X, no cross-iter prefetch).
// B=32, N=4096, D=256, K=128, Dc=64.
//
// ROUND-7 POST-MORTEM: VGPR=256 + 167MB/60MB phantom fetch/write = pressure
// spill. Cause localized: xp[16] (64 VGPR) prefetch held live across the GEMM
// section -> peak ~294 regs > 256 cap -> ~40 regs spilled per iter.
// FIX: issue all 16 X loads at ITER START (MLP preserved, staged vmcnt),
// pack immediately, xp dead before first MFMA. Peak ~230 <= 256. Cost: one
// exposed HBM round-trip per iter (~3 us total) vs ~130 us of spill traffic.
//
// Phase1: grid 256 (8 blocks/batch, 512 rows), 256 thr (4 waves), 1 blk/CU.
//   Each wave owns 128 rows (8 iters x 16) and computes ALL 12 weight tiles.
//   Weights (8 Wa + 4 W1) in LDS as B-frags (96 KB, read-only).
//   ZERO __syncthreads in the main loop — waves fully independent.
//   Softmax wave-local: 8 kt regs + shfl_xor(1,2,4,8) within quad.
//   U = assign^T·h in-register via zero-padded 16x16x32 MFMA (contraction
//   slot c=q*8+r on both operands, slots 4-7 zero -> contracts the 16 rows).
//   Flush: block LDS tree-reduce (weights area dead) -> per-block partials,
//   hand-unrolled with LITERAL uacc indices (rule-#20 immunity, rounds-5/6 bug).
// Phase2: per batch, sum 8 partials, vlad = U_tot@W2^T + mass*(b2-centroid),
//   L2-normalize.
//
// MFMA 16x16x32 layouts (m89/m120-verified):
//   A: lane holds A[m=lane&15][c=(lane>>4)*8+j]
//   B: lane holds B[c=(lane>>4)*8+j][n=lane&15]
//   C/D: lane holds D[row=(lane>>4)*4+r][col=lane&15]

#define B_   32
#define N_   4096
#define D_   256
#define K_   128
#define DC_  64
#define ITERS 8           // 16-row iters per wave (128 rows/wave, 512/block)
#define NEG  0.01f

typedef __attribute__((ext_vector_type(8))) short bf16x8;
typedef __attribute__((ext_vector_type(4))) float f32x4;

// LDS: 96 KB weight B-frags [g=0..11][ks=0..7][lane][16B]; flush reuses
// bytes 0..32767 (U reduce, 4 waves x 8KB) + 65536..67583 (mass reduce).
#define LDS_BYTES 98304

__device__ __forceinline__ unsigned short f2bf(float x) {
  union { float f; unsigned u; } v; v.f = x;
  unsigned r = v.u + 0x7fffu + ((v.u >> 16) & 1u);
  return (unsigned short)(r >> 16);
}
__device__ __forceinline__ unsigned pack2(float a, float b) {
  return (unsigned)f2bf(a) | ((unsigned)f2bf(b) << 16);
}
__device__ __forceinline__ bf16x8 ldf(const char* s, int off) {
  return *reinterpret_cast<const bf16x8*>(s + off);
}
__device__ __forceinline__ bf16x8 fragz(unsigned lo, unsigned hi) {
  union { unsigned u[4]; bf16x8 v; } t;
  t.u[0] = lo; t.u[1] = hi; t.u[2] = 0u; t.u[3] = 0u;
  return t.v;
}
__device__ __forceinline__ bf16x8 pack8(float4 a, float4 c) {
  union { unsigned u[4]; bf16x8 v; } t;
  t.u[0] = pack2(a.x, a.y); t.u[1] = pack2(a.z, a.w);
  t.u[2] = pack2(c.x, c.y); t.u[3] = pack2(c.z, c.w);
  return t.v;
}

__global__ __launch_bounds__(256, 1)
void netvlad_phase1(const float* __restrict__ desc, const float* __restrict__ W1,
                    const float* __restrict__ b1, const float* __restrict__ Wa,
                    const float* __restrict__ ba,
                    float* __restrict__ ws_u, float* __restrict__ ws_m)
{
  extern __shared__ char smem[];
  const int t    = threadIdx.x;
  const int b    = blockIdx.x >> 3;
  const int blk  = blockIdx.x & 7;
  const int w    = t >> 6;         // wave 0..3
  const int lane = t & 63;
  const int li   = lane & 15;
  const int q    = lane >> 4;

  // ---- weights -> LDS B-frags (the only cooperative phase) ----
  for (int p = t; p < 6144; p += 256) {
    int L = p & 63, ks = (p >> 6) & 7, g = p >> 9;   // g: 0..7 Wa, 8..11 W1
    const float* src = (g < 8 ? Wa + (size_t)(g * 16 + (L & 15)) * D_
                              : W1 + (size_t)((g - 8) * 16 + (L & 15)) * D_)
                       + ks * 32 + ((L >> 4) << 3);
    float4 a = *(const float4*)src, c = *(const float4*)(src + 4);
    uint4 o;
    o.x = pack2(a.x, a.y); o.y = pack2(a.z, a.w);
    o.z = pack2(c.x, c.y); o.w = pack2(c.z, c.w);
    *reinterpret_cast<uint4*>(smem + ((g * 8 + ks) * 64 + L) * 16) = o;
  }

  float bar[8], b1r[4];
  #pragma unroll
  for (int kt = 0; kt < 8; ++kt) bar[kt] = ba[kt * 16 + li];
  #pragma unroll
  for (int et = 0; et < 4; ++et) b1r[et] = b1[et * 16 + li];

  f32x4 uacc[4][8];                 // U^T[e=et*16+q*4+r][k=kt*16+li]
  #pragma unroll
  for (int et = 0; et < 4; ++et)
    #pragma unroll
    for (int kt = 0; kt < 8; ++kt) uacc[et][kt] = (f32x4){0.f, 0.f, 0.f, 0.f};
  float mreg[8] = {0.f, 0.f, 0.f, 0.f, 0.f, 0.f, 0.f, 0.f};

  const int rowb = blk * 512 + w * 128;

  __syncthreads();                  // weights staged; last barrier before flush

  for (int it = 0; it < ITERS; ++it) {
    // ---- X rows: issue all 16 loads (MLP), pack, xp dead before MFMAs ----
    // NO cross-iteration prefetch: holding xp across the GEMMs was round-7's
    // 294-reg peak -> pressure spill. Load-at-use keeps peak ~230 <= 256.
    const float* xb = desc + ((size_t)b * N_ + rowb + it * 16 + li) * D_ + q * 8;
    float4 xp[16];
    #pragma unroll
    for (int ks = 0; ks < 8; ++ks) {
      xp[2 * ks]     = *(const float4*)(xb + ks * 32);
      xp[2 * ks + 1] = *(const float4*)(xb + ks * 32 + 4);
    }
    bf16x8 xf[8];
    #pragma unroll
    for (int ks = 0; ks < 8; ++ks) xf[ks] = pack8(xp[2 * ks], xp[2 * ks + 1]);

    // ---- h = X @ W1^T + b1, LeakyReLU, pack (C-layout == A-frag content) ----
    f32x4 hh[4];
    #pragma unroll
    for (int et = 0; et < 4; ++et) hh[et] = (f32x4){0.f, 0.f, 0.f, 0.f};
    #pragma unroll
    for (int ks = 0; ks < 8; ++ks)
      #pragma unroll
      for (int et = 0; et < 4; ++et)
        hh[et] = __builtin_amdgcn_mfma_f32_16x16x32_bf16(
            xf[ks], ldf(smem, (((8 + et) * 8 + ks) * 64 + lane) * 16), hh[et], 0, 0, 0);
    uint2 hpk[4];
    #pragma unroll
    for (int et = 0; et < 4; ++et) {
      float v0 = hh[et][0] + b1r[et], v1 = hh[et][1] + b1r[et];
      float v2 = hh[et][2] + b1r[et], v3 = hh[et][3] + b1r[et];
      v0 = v0 >= 0.f ? v0 : NEG * v0;  v1 = v1 >= 0.f ? v1 : NEG * v1;
      v2 = v2 >= 0.f ? v2 : NEG * v2;  v3 = v3 >= 0.f ? v3 : NEG * v3;
      hpk[et].x = pack2(v0, v1); hpk[et].y = pack2(v2, v3);
    }

    // ---- logits = X @ Wa^T + ba ----
    f32x4 accL[8];
    #pragma unroll
    for (int kt = 0; kt < 8; ++kt) accL[kt] = (f32x4){0.f, 0.f, 0.f, 0.f};
    #pragma unroll
    for (int ks = 0; ks < 8; ++ks)
      #pragma unroll
      for (int kt = 0; kt < 8; ++kt)
        accL[kt] = __builtin_amdgcn_mfma_f32_16x16x32_bf16(
            xf[ks], ldf(smem, ((kt * 8 + ks) * 64 + lane) * 16), accL[kt], 0, 0, 0);
    #pragma unroll
    for (int kt = 0; kt < 8; ++kt) {
      accL[kt][0] += bar[kt]; accL[kt][1] += bar[kt];
      accL[kt][2] += bar[kt]; accL[kt][3] += bar[kt];
    }

    // ---- wave-local softmax per row (k lives in {kt regs} x {li lanes}) ----
    float inv4[4];
    #pragma unroll
    for (int r = 0; r < 4; ++r) {
      float m = accL[0][r];
      #pragma unroll
      for (int kt = 1; kt < 8; ++kt) m = fmaxf(m, accL[kt][r]);
      #pragma unroll
      for (int off = 1; off < 16; off <<= 1) m = fmaxf(m, __shfl_xor(m, off, 64));
      float s = 0.f;
      #pragma unroll
      for (int kt = 0; kt < 8; ++kt) {
        float e = __expf(accL[kt][r] - m); accL[kt][r] = e; s += e;
      }
      #pragma unroll
      for (int off = 1; off < 16; off <<= 1) s += __shfl_xor(s, off, 64);
      inv4[r] = 1.0f / s;
    }

    // ---- U += assign^T · h via zero-padded 16x16x32 (contract 16 rows) ----
    #pragma unroll
    for (int kt = 0; kt < 8; ++kt) {
      float a0 = accL[kt][0] * inv4[0], a1 = accL[kt][1] * inv4[1];
      float a2 = accL[kt][2] * inv4[2], a3 = accL[kt][3] * inv4[3];
      mreg[kt] += a0 + a1 + a2 + a3;
      bf16x8 af = fragz(pack2(a0, a1), pack2(a2, a3));
      #pragma unroll
      for (int et = 0; et < 4; ++et)
        uacc[et][kt] = __builtin_amdgcn_mfma_f32_16x16x32_bf16(
            fragz(hpk[et].x, hpk[et].y), af, uacc[et][kt], 0, 0, 0);
    }
  }

  // ---- mass: cross-quad reduce (rows live in quads) ----
  #pragma unroll
  for (int kt = 0; kt < 8; ++kt) {
    float v = mreg[kt];
    v += __shfl_xor(v, 16, 64);
    v += __shfl_xor(v, 32, 64);
    mreg[kt] = v;
  }

  // ---- flush: block tree-reduce in LDS, plain stores. HAND-UNROLLED with
  // literal et/kt so no loop variable EVER indexes uacc (rule #20 immunity;
  // the rounds-5/6 500MB-scratch bug). Inner loops index LDS/global only.
  const size_t obase = (size_t)(b * 8 + blk) * 4 * 2048;

#define UST(ET, KT) \
  *reinterpret_cast<f32x4*>(smem + ((w * 8 + KT) * 64 + lane) * 16) = uacc[ET][KT];
#define USTROW(ET) \
  UST(ET, 0) UST(ET, 1) UST(ET, 2) UST(ET, 3) UST(ET, 4) UST(ET, 5) UST(ET, 6) UST(ET, 7)
#define MST(KT) \
  *reinterpret_cast<float*>(smem + 65536 + (w * 128 + KT * 16 + lane) * 4) = mreg[KT];

#define FLUSH_ET(ET)                                                          \
  __syncthreads();                                                            \
  USTROW(ET)                                                                  \
  if (ET == 0 && lane < 16) {                                                 \
    MST(0) MST(1) MST(2) MST(3) MST(4) MST(5) MST(6) MST(7)                   \
  }                                                                           \
  __syncthreads();                                                            \
  {                                                                           \
    _Pragma("unroll")                                                         \
    for (int c = 0; c < 2; ++c) {                                             \
      const int idx = t + c * 256;                                            \
      float4 s = {0.f, 0.f, 0.f, 0.f};                                        \
      _Pragma("unroll")                                                       \
      for (int p = 0; p < 4; ++p) {                                           \
        float4 v = *reinterpret_cast<const float4*>(smem + p * 8192 + idx * 16); \
        s.x += v.x; s.y += v.y; s.z += v.z; s.w += v.w;                       \
      }                                                                       \
      *reinterpret_cast<float4*>(ws_u + obase + ET * 2048 + idx * 4) = s;     \
    }                                                                         \
    if (ET == 0 && t < 128) {                                                 \
      float sm = 0.f;                                                         \
      _Pragma("unroll")                                                       \
      for (int p = 0; p < 4; ++p)                                             \
        sm += *reinterpret_cast<const float*>(smem + 65536 + (p * 128 + t) * 4); \
      ws_m[(b * 8 + blk) * 128 + t] = sm;                                     \
    }                                                                         \
  }

  FLUSH_ET(0)
  FLUSH_ET(1)
  FLUSH_ET(2)
  FLUSH_ET(3)

#undef FLUSH_ET
#undef MST
#undef USTROW
#undef UST
}

__global__ __launch_bounds__(1024)
void netvlad_phase2(const float* __restrict__ ws_u, const float* __restrict__ ws_m,
                    const float* __restrict__ W2, const float* __restrict__ b2,
                    const float* __restrict__ centroid, float* __restrict__ out)
{
  __shared__ float u[DC_ * K_];      // [e][k]  32 KB
  __shared__ float w2t[DC_ * DC_];   // [e][d]  16 KB
  __shared__ float msh[K_];
  __shared__ float red[17];
  const int b = blockIdx.x, t = threadIdx.x;

  // sum 8 block-partials; decode frag layout -> [e][k]
  for (int idx = t; idx < 8192; idx += 1024) {
    int et = idx >> 11, j = idx & 2047;
    int kt = j >> 8, ln = (j >> 2) & 63, r = j & 3;
    int e = et * 16 + (ln >> 4) * 4 + r, k = kt * 16 + (ln & 15);
    float s = 0.f;
    #pragma unroll
    for (int p = 0; p < 8; ++p)
      s += ws_u[((size_t)(b * 8 + p) * 4 + et) * 2048 + j];
    u[e * K_ + k] = s;
  }
  for (int idx = t; idx < DC_ * DC_; idx += 1024)
    w2t[(idx & 63) * 64 + (idx >> 6)] = W2[idx];   // w2t[e][d] = W2[d][e]
  if (t < K_) {
    float s = 0.f;
    #pragma unroll
    for (int p = 0; p < 8; ++p) s += ws_m[(b * 8 + p) * 128 + t];
    msh[t] = s;
  }
  __syncthreads();

  // vlad[k][d0..d0+7] = sum_e u[e][k]*W2[d][e] + mass[k]*(b2[d]-centroid[k][d])
  const int k = t >> 3, d0 = (t & 7) * 8;
  float acc[8] = {0.f, 0.f, 0.f, 0.f, 0.f, 0.f, 0.f, 0.f};
  #pragma unroll 8
  for (int e = 0; e < DC_; ++e) {
    float uk = u[e * K_ + k];
    float4 wa = *(const float4*)&w2t[e * 64 + d0];
    float4 wb = *(const float4*)&w2t[e * 64 + d0 + 4];
    acc[0] += uk * wa.x; acc[1] += uk * wa.y; acc[2] += uk * wa.z; acc[3] += uk * wa.w;
    acc[4] += uk * wb.x; acc[5] += uk * wb.y; acc[6] += uk * wb.z; acc[7] += uk * wb.w;
  }
  const float mk = msh[k];
  const float* cb = centroid + k * 64 + d0;
  const float* bb = b2 + d0;
  #pragma unroll
  for (int j = 0; j < 8; ++j) acc[j] += mk * (bb[j] - cb[j]);

  float ss = 0.f;
  #pragma unroll
  for (int j = 0; j < 8; ++j) ss += acc[j] * acc[j];
  #pragma unroll
  for (int off = 32; off > 0; off >>= 1) ss += __shfl_down(ss, off, 64);
  if ((t & 63) == 0) red[t >> 6] = ss;
  __syncthreads();
  if (t == 0) {
    float s = 0.f;
    #pragma unroll
    for (int i = 0; i < 16; ++i) s += red[i];
    red[16] = 1.0f / fmaxf(sqrtf(s), 1e-12f);
  }
  __syncthreads();
  const float inv = red[16];
  float* op = out + (size_t)b * (K_ * DC_) + k * 64 + d0;
  float4 o0 = {acc[0] * inv, acc[1] * inv, acc[2] * inv, acc[3] * inv};
  float4 o1 = {acc[4] * inv, acc[5] * inv, acc[6] * inv, acc[7] * inv};
  *reinterpret_cast<float4*>(op)     = o0;
  *reinterpret_cast<float4*>(op + 4) = o1;
}

extern "C" void kernel_launch(void* const* d_in, const int* in_sizes, int n_in,
                              void* d_out, int out_size, void* d_ws, size_t ws_size,
                              hipStream_t stream) {
  const float* desc     = (const float*)d_in[0];
  const float* W1       = (const float*)d_in[1];
  const float* b1       = (const float*)d_in[2];
  const float* W2       = (const float*)d_in[3];
  const float* b2       = (const float*)d_in[4];
  const float* Wa       = (const float*)d_in[5];
  const float* ba       = (const float*)d_in[6];
  const float* centroid = (const float*)d_in[7];
  float* out = (float*)d_out;

  float* ws_u = (float*)d_ws;                      // 256 blocks x 8192 f32 = 8 MB
  float* ws_m = ws_u + (size_t)B_ * 8 * 4 * 2048;  // 256 x 128 f32 = 128 KB

  hipFuncSetAttribute(reinterpret_cast<const void*>(netvlad_phase1),
                      hipFuncAttributeMaxDynamicSharedMemorySize, LDS_BYTES);

  netvlad_phase1<<<dim3(B_ * 8), dim3(256), LDS_BYTES, stream>>>(
      desc, W1, b1, Wa, ba, ws_u, ws_m);
  netvlad_phase2<<<dim3(B_), dim3(1024), 0, stream>>>(
      ws_u, ws_m, W2, b2, centroid, out);
}

// Round 7
// 307.935 us; speedup vs baseline: 1.2079x; 1.2079x over previous
//
#include <hip/hip_runtime.h>

// NetVLAD — round 9: e-split wave pairs -> uacc halved -> spill structurally gone.
// B=32, N=4096, D=256, K=128, Dc=64.
//
// ROUNDS 7/8 POST-MORTEM: VGPR_Count pinned at 256 with ~100MB phantom traffic
// both rounds. Live-set math: persistent ~170 (uacc 128!) + xp 64 + xf 32 = 266
// > 256 cap even load-at-use. The 128-reg uacc makes the design ~15-40 regs
// over budget no matter how loads are scheduled.
// FIX: wave PAIRS share 256 rows. Both waves compute full logits+softmax for
// the pair's rows (duplicated; logits GEMM is cheap); each wave computes only
// HALF the e-tiles of h and U -> uacc[2][8] = 64 VGPRs. Peak ~223 < 256 WITH
// cross-iter X prefetch restored (needed: 1 wave/SIMD has no TLP).
// Duplicate X reads are same-CU -> L2 hits, HBM fetch unchanged.
//
// Phase1: grid 256 (8 blocks/batch, 512 rows), 256 thr (4 waves), 1 blk/CU.
//   pair=w>>1 owns rows [blk*512+pair*256, +256), 16 iters x 16 rows; eh=w&1
//   picks e-half. Weights (8 Wa + 4 W1) in LDS as B-frags (96 KB, read-only).
//   ZERO __syncthreads in the main loop. Softmax wave-local.
//   U = assign^T·h in-register via zero-padded 16x16x32 MFMA (contraction
//   slot c=q*8+r on both operands, slots 4-7 zero -> contracts the 16 rows).
//   Flush: 2 rounds (one per e2); per round the 4 waves park uacc[e2] in LDS,
//   threads sum pair0+pair1 -> per-block partials. Literal uacc indices
//   everywhere (rule-#20 immunity).
// Phase2: per batch, sum 8 partials, vlad = U_tot@W2^T + mass*(b2-centroid),
//   L2-normalize.
//
// MFMA 16x16x32 layouts (m89/m120-verified):
//   A: lane holds A[m=lane&15][c=(lane>>4)*8+j]
//   B: lane holds B[c=(lane>>4)*8+j][n=lane&15]
//   C/D: lane holds D[row=(lane>>4)*4+r][col=lane&15]

#define B_   32
#define N_   4096
#define D_   256
#define K_   128
#define DC_  64
#define ITERS 16          // 16-row iters per wave pair (256 rows/pair)
#define NEG  0.01f

typedef __attribute__((ext_vector_type(8))) short bf16x8;
typedef __attribute__((ext_vector_type(4))) float f32x4;

// LDS: 96 KB weight B-frags [g=0..11][ks=0..7][lane][16B]; flush reuses
// bytes 0..32767 (4 wave slots x 8KB) + 65536..66559 (mass, 2 pairs x 512B).
#define LDS_BYTES 98304

__device__ __forceinline__ unsigned short f2bf(float x) {
  union { float f; unsigned u; } v; v.f = x;
  unsigned r = v.u + 0x7fffu + ((v.u >> 16) & 1u);
  return (unsigned short)(r >> 16);
}
__device__ __forceinline__ unsigned pack2(float a, float b) {
  return (unsigned)f2bf(a) | ((unsigned)f2bf(b) << 16);
}
__device__ __forceinline__ bf16x8 ldf(const char* s, int off) {
  return *reinterpret_cast<const bf16x8*>(s + off);
}
__device__ __forceinline__ bf16x8 fragz(unsigned lo, unsigned hi) {
  union { unsigned u[4]; bf16x8 v; } t;
  t.u[0] = lo; t.u[1] = hi; t.u[2] = 0u; t.u[3] = 0u;
  return t.v;
}
__device__ __forceinline__ bf16x8 pack8(float4 a, float4 c) {
  union { unsigned u[4]; bf16x8 v; } t;
  t.u[0] = pack2(a.x, a.y); t.u[1] = pack2(a.z, a.w);
  t.u[2] = pack2(c.x, c.y); t.u[3] = pack2(c.z, c.w);
  return t.v;
}

__global__ __launch_bounds__(256, 1)
void netvlad_phase1(const float* __restrict__ desc, const float* __restrict__ W1,
                    const float* __restrict__ b1, const float* __restrict__ Wa,
                    const float* __restrict__ ba,
                    float* __restrict__ ws_u, float* __restrict__ ws_m)
{
  extern __shared__ char smem[];
  const int t    = threadIdx.x;
  const int b    = blockIdx.x >> 3;
  const int blk  = blockIdx.x & 7;
  const int w    = t >> 6;         // wave 0..3
  const int lane = t & 63;
  const int li   = lane & 15;
  const int q    = lane >> 4;
  const int pair = w >> 1;         // row-group (256 rows)
  const int eh   = w & 1;          // e-half (et global = eh*2 + e2)

  // ---- weights -> LDS B-frags (the only cooperative phase) ----
  for (int p = t; p < 6144; p += 256) {
    int L = p & 63, ks = (p >> 6) & 7, g = p >> 9;   // g: 0..7 Wa, 8..11 W1
    const float* src = (g < 8 ? Wa + (size_t)(g * 16 + (L & 15)) * D_
                              : W1 + (size_t)((g - 8) * 16 + (L & 15)) * D_)
                       + ks * 32 + ((L >> 4) << 3);
    float4 a = *(const float4*)src, c = *(const float4*)(src + 4);
    uint4 o;
    o.x = pack2(a.x, a.y); o.y = pack2(a.z, a.w);
    o.z = pack2(c.x, c.y); o.w = pack2(c.z, c.w);
    *reinterpret_cast<uint4*>(smem + ((g * 8 + ks) * 64 + L) * 16) = o;
  }

  float bar[8], b1r[2];
  #pragma unroll
  for (int kt = 0; kt < 8; ++kt) bar[kt] = ba[kt * 16 + li];
  #pragma unroll
  for (int e2 = 0; e2 < 2; ++e2) b1r[e2] = b1[(eh * 2 + e2) * 16 + li];

  f32x4 uacc[2][8];                 // U^T[e=(eh*2+e2)*16+q*4+r][k=kt*16+li]
  #pragma unroll
  for (int e2 = 0; e2 < 2; ++e2)
    #pragma unroll
    for (int kt = 0; kt < 8; ++kt) uacc[e2][kt] = (f32x4){0.f, 0.f, 0.f, 0.f};
  float mreg[8] = {0.f, 0.f, 0.f, 0.f, 0.f, 0.f, 0.f, 0.f};

  // ---- cross-iter X prefetch (fits now: peak ~223 < 256) ----
  const int rowb = blk * 512 + pair * 256;
  float4 xp[16];
  auto issueX = [&](int itn) {
    const float* xb = desc + ((size_t)b * N_ + rowb + itn * 16 + li) * D_ + q * 8;
    #pragma unroll
    for (int ks = 0; ks < 8; ++ks) {
      xp[2 * ks]     = *(const float4*)(xb + ks * 32);
      xp[2 * ks + 1] = *(const float4*)(xb + ks * 32 + 4);
    }
  };
  issueX(0);

  __syncthreads();                  // weights staged; last barrier before flush

  for (int it = 0; it < ITERS; ++it) {
    // ---- pack current X, immediately issue next iter's loads ----
    bf16x8 xf[8];
    #pragma unroll
    for (int ks = 0; ks < 8; ++ks) xf[ks] = pack8(xp[2 * ks], xp[2 * ks + 1]);
    if (it + 1 < ITERS) issueX(it + 1);

    // ---- h half: 2 et tiles = X @ W1^T + b1, LeakyReLU, pack ----
    f32x4 hh[2];
    hh[0] = (f32x4){0.f, 0.f, 0.f, 0.f};
    hh[1] = (f32x4){0.f, 0.f, 0.f, 0.f};
    #pragma unroll
    for (int ks = 0; ks < 8; ++ks)
      #pragma unroll
      for (int e2 = 0; e2 < 2; ++e2)
        hh[e2] = __builtin_amdgcn_mfma_f32_16x16x32_bf16(
            xf[ks], ldf(smem, (((8 + eh * 2 + e2) * 8 + ks) * 64 + lane) * 16),
            hh[e2], 0, 0, 0);
    uint2 hpk[2];
    #pragma unroll
    for (int e2 = 0; e2 < 2; ++e2) {
      float v0 = hh[e2][0] + b1r[e2], v1 = hh[e2][1] + b1r[e2];
      float v2 = hh[e2][2] + b1r[e2], v3 = hh[e2][3] + b1r[e2];
      v0 = v0 >= 0.f ? v0 : NEG * v0;  v1 = v1 >= 0.f ? v1 : NEG * v1;
      v2 = v2 >= 0.f ? v2 : NEG * v2;  v3 = v3 >= 0.f ? v3 : NEG * v3;
      hpk[e2].x = pack2(v0, v1); hpk[e2].y = pack2(v2, v3);
    }

    // ---- logits = X @ Wa^T + ba (full K; duplicated across the pair) ----
    f32x4 accL[8];
    #pragma unroll
    for (int kt = 0; kt < 8; ++kt) accL[kt] = (f32x4){0.f, 0.f, 0.f, 0.f};
    #pragma unroll
    for (int ks = 0; ks < 8; ++ks)
      #pragma unroll
      for (int kt = 0; kt < 8; ++kt)
        accL[kt] = __builtin_amdgcn_mfma_f32_16x16x32_bf16(
            xf[ks], ldf(smem, ((kt * 8 + ks) * 64 + lane) * 16), accL[kt], 0, 0, 0);
    #pragma unroll
    for (int kt = 0; kt < 8; ++kt) {
      accL[kt][0] += bar[kt]; accL[kt][1] += bar[kt];
      accL[kt][2] += bar[kt]; accL[kt][3] += bar[kt];
    }

    // ---- wave-local softmax per row ----
    float inv4[4];
    #pragma unroll
    for (int r = 0; r < 4; ++r) {
      float m = accL[0][r];
      #pragma unroll
      for (int kt = 1; kt < 8; ++kt) m = fmaxf(m, accL[kt][r]);
      #pragma unroll
      for (int off = 1; off < 16; off <<= 1) m = fmaxf(m, __shfl_xor(m, off, 64));
      float s = 0.f;
      #pragma unroll
      for (int kt = 0; kt < 8; ++kt) {
        float e = __expf(accL[kt][r] - m); accL[kt][r] = e; s += e;
      }
      #pragma unroll
      for (int off = 1; off < 16; off <<= 1) s += __shfl_xor(s, off, 64);
      inv4[r] = 1.0f / s;
    }

    // ---- U += assign^T · h (own e-half) via zero-padded MFMA ----
    #pragma unroll
    for (int kt = 0; kt < 8; ++kt) {
      float a0 = accL[kt][0] * inv4[0], a1 = accL[kt][1] * inv4[1];
      float a2 = accL[kt][2] * inv4[2], a3 = accL[kt][3] * inv4[3];
      mreg[kt] += a0 + a1 + a2 + a3;
      bf16x8 af = fragz(pack2(a0, a1), pack2(a2, a3));
      #pragma unroll
      for (int e2 = 0; e2 < 2; ++e2)
        uacc[e2][kt] = __builtin_amdgcn_mfma_f32_16x16x32_bf16(
            fragz(hpk[e2].x, hpk[e2].y), af, uacc[e2][kt], 0, 0, 0);
    }
  }

  // ---- mass: cross-quad reduce (rows live in quads) ----
  #pragma unroll
  for (int kt = 0; kt < 8; ++kt) {
    float v = mreg[kt];
    v += __shfl_xor(v, 16, 64);
    v += __shfl_xor(v, 32, 64);
    mreg[kt] = v;
  }

  // ---- flush: 2 rounds (e2=0,1). Wave w parks uacc[e2] in slot w; threads
  // sum pair0+pair1 per e-half. LITERAL uacc indices only (rule #20).
  // Mass (pair-duplicated) stored by eh==0 waves only, in round 0.
  const size_t obase = (size_t)(b * 8 + blk) * 4 * 2048;

#define UST(E2, KT) \
  *reinterpret_cast<f32x4*>(smem + ((w * 8 + KT) * 64 + lane) * 16) = uacc[E2][KT];
#define USTROW(E2) \
  UST(E2, 0) UST(E2, 1) UST(E2, 2) UST(E2, 3) UST(E2, 4) UST(E2, 5) UST(E2, 6) UST(E2, 7)
#define MST(KT) \
  *reinterpret_cast<float*>(smem + 65536 + (pair * 128 + KT * 16 + lane) * 4) = mreg[KT];

#define FLUSH_E2(E2)                                                          \
  __syncthreads();                                                            \
  USTROW(E2)                                                                  \
  if (E2 == 0 && eh == 0 && lane < 16) {                                      \
    MST(0) MST(1) MST(2) MST(3) MST(4) MST(5) MST(6) MST(7)                   \
  }                                                                           \
  __syncthreads();                                                            \
  {                                                                           \
    _Pragma("unroll")                                                         \
    for (int c = 0; c < 2; ++c) {                                             \
      const int idx = t + c * 256;                                            \
      float4 va = *reinterpret_cast<const float4*>(smem + 0 * 8192 + idx * 16); \
      float4 vb = *reinterpret_cast<const float4*>(smem + 2 * 8192 + idx * 16); \
      float4 sa = {va.x + vb.x, va.y + vb.y, va.z + vb.z, va.w + vb.w};       \
      *reinterpret_cast<float4*>(ws_u + obase + E2 * 2048 + idx * 4) = sa;    \
      float4 vc = *reinterpret_cast<const float4*>(smem + 1 * 8192 + idx * 16); \
      float4 vd = *reinterpret_cast<const float4*>(smem + 3 * 8192 + idx * 16); \
      float4 sb = {vc.x + vd.x, vc.y + vd.y, vc.z + vd.z, vc.w + vd.w};       \
      *reinterpret_cast<float4*>(ws_u + obase + (2 + E2) * 2048 + idx * 4) = sb; \
    }                                                                         \
    if (E2 == 0 && t < 128) {                                                 \
      const float* mf = reinterpret_cast<const float*>(smem + 65536);         \
      ws_m[(b * 8 + blk) * 128 + t] = mf[t] + mf[128 + t];                    \
    }                                                                         \
  }

  FLUSH_E2(0)
  FLUSH_E2(1)

#undef FLUSH_E2
#undef MST
#undef USTROW
#undef UST
}

__global__ __launch_bounds__(1024)
void netvlad_phase2(const float* __restrict__ ws_u, const float* __restrict__ ws_m,
                    const float* __restrict__ W2, const float* __restrict__ b2,
                    const float* __restrict__ centroid, float* __restrict__ out)
{
  __shared__ float u[DC_ * K_];      // [e][k]  32 KB
  __shared__ float w2t[DC_ * DC_];   // [e][d]  16 KB
  __shared__ float msh[K_];
  __shared__ float red[17];
  const int b = blockIdx.x, t = threadIdx.x;

  // sum 8 block-partials; decode frag layout -> [e][k]
  for (int idx = t; idx < 8192; idx += 1024) {
    int et = idx >> 11, j = idx & 2047;
    int kt = j >> 8, ln = (j >> 2) & 63, r = j & 3;
    int e = et * 16 + (ln >> 4) * 4 + r, k = kt * 16 + (ln & 15);
    float s = 0.f;
    #pragma unroll
    for (int p = 0; p < 8; ++p)
      s += ws_u[((size_t)(b * 8 + p) * 4 + et) * 2048 + j];
    u[e * K_ + k] = s;
  }
  for (int idx = t; idx < DC_ * DC_; idx += 1024)
    w2t[(idx & 63) * 64 + (idx >> 6)] = W2[idx];   // w2t[e][d] = W2[d][e]
  if (t < K_) {
    float s = 0.f;
    #pragma unroll
    for (int p = 0; p < 8; ++p) s += ws_m[(b * 8 + p) * 128 + t];
    msh[t] = s;
  }
  __syncthreads();

  // vlad[k][d0..d0+7] = sum_e u[e][k]*W2[d][e] + mass[k]*(b2[d]-centroid[k][d])
  const int k = t >> 3, d0 = (t & 7) * 8;
  float acc[8] = {0.f, 0.f, 0.f, 0.f, 0.f, 0.f, 0.f, 0.f};
  #pragma unroll 8
  for (int e = 0; e < DC_; ++e) {
    float uk = u[e * K_ + k];
    float4 wa = *(const float4*)&w2t[e * 64 + d0];
    float4 wb = *(const float4*)&w2t[e * 64 + d0 + 4];
    acc[0] += uk * wa.x; acc[1] += uk * wa.y; acc[2] += uk * wa.z; acc[3] += uk * wa.w;
    acc[4] += uk * wb.x; acc[5] += uk * wb.y; acc[6] += uk * wb.z; acc[7] += uk * wb.w;
  }
  const float mk = msh[k];
  const float* cb = centroid + k * 64 + d0;
  const float* bb = b2 + d0;
  #pragma unroll
  for (int j = 0; j < 8; ++j) acc[j] += mk * (bb[j] - cb[j]);

  float ss = 0.f;
  #pragma unroll
  for (int j = 0; j < 8; ++j) ss += acc[j] * acc[j];
  #pragma unroll
  for (int off = 32; off > 0; off >>= 1) ss += __shfl_down(ss, off, 64);
  if ((t & 63) == 0) red[t >> 6] = ss;
  __syncthreads();
  if (t == 0) {
    float s = 0.f;
    #pragma unroll
    for (int i = 0; i < 16; ++i) s += red[i];
    red[16] = 1.0f / fmaxf(sqrtf(s), 1e-12f);
  }
  __syncthreads();
  const float inv = red[16];
  float* op = out + (size_t)b * (K_ * DC_) + k * 64 + d0;
  float4 o0 = {acc[0] * inv, acc[1] * inv, acc[2] * inv, acc[3] * inv};
  float4 o1 = {acc[4] * inv, acc[5] * inv, acc[6] * inv, acc[7] * inv};
  *reinterpret_cast<float4*>(op)     = o0;
  *reinterpret_cast<float4*>(op + 4) = o1;
}

extern "C" void kernel_launch(void* const* d_in, const int* in_sizes, int n_in,
                              void* d_out, int out_size, void* d_ws, size_t ws_size,
                              hipStream_t stream) {
  const float* desc     = (const float*)d_in[0];
  const float* W1       = (const float*)d_in[1];
  const float* b1       = (const float*)d_in[2];
  const float* W2       = (const float*)d_in[3];
  const float* b2       = (const float*)d_in[4];
  const float* Wa       = (const float*)d_in[5];
  const float* ba       = (const float*)d_in[6];
  const float* centroid = (const float*)d_in[7];
  float* out = (float*)d_out;

  float* ws_u = (float*)d_ws;                      // 256 blocks x 8192 f32 = 8 MB
  float* ws_m = ws_u + (size_t)B_ * 8 * 4 * 2048;  // 256 x 128 f32 = 128 KB

  hipFuncSetAttribute(reinterpret_cast<const void*>(netvlad_phase1),
                      hipFuncAttributeMaxDynamicSharedMemorySize, LDS_BYTES);

  netvlad_phase1<<<dim3(B_ * 8), dim3(256), LDS_BYTES, stream>>>(
      desc, W1, b1, Wa, ba, ws_u, ws_m);
  netvlad_phase2<<<dim3(B_), dim3(1024), 0, stream>>>(
      ws_u, ws_m, W2, b2, centroid, out);
}